// Round 1
// baseline (18888.585 us; speedup 1.0000x reference)
//
#include <hip/hip_runtime.h>
#include <hip/hip_cooperative_groups.h>

namespace cg = cooperative_groups;

static constexpr int L_  = 2;
static constexpr int H_  = 1024;
static constexpr int E_  = 1024;
static constexpr int T_  = 64;
static constexpr int BT  = 256;   // threads per block (4 waves)
static constexpr int PBLK = 128;  // blocks participating in softmax/feedback phase
static constexpr int ROWS_PER_PBLK = E_ / PBLK;  // 8

__device__ __forceinline__ float sigm(float v) { return 1.0f / (1.0f + expf(-v)); }

__global__ __launch_bounds__(BT, 4) void ctrl_kernel(
    const float* __restrict__ W_ih, const float* __restrict__ W_hh,
    const float* __restrict__ b_ih, const float* __restrict__ b_hh,
    const float* __restrict__ We,   const float* __restrict__ be,
    float* __restrict__ out, float* __restrict__ ws)
{
  cg::grid_group gg = cg::this_grid();
  const int tid  = threadIdx.x;
  const int bid  = blockIdx.x;
  const int nb   = gridDim.x;
  const int lane = tid & 63;
  const int wv   = tid >> 6;
  const int c0   = tid * 4;        // 256 threads x 4 floats = 1024 cols

  // workspace layout (floats)
  float* xv      = ws;                     // H      : feedback input x
  float* hbuf    = ws + H_;                // 2*L*H  : h double buffer
  float* cst     = hbuf + 2 * L_ * H_;     // L*H    : cell state
  float* logits  = cst + L_ * H_;          // E
  float* partial = logits + E_;            // PBLK*H : x_next partials

  // zero-init state every call (harness does not re-poison between replays)
  const int initN = H_ + 2 * L_ * H_ + L_ * H_ + E_;
  for (int i = bid * BT + tid; i < initN; i += nb * BT) ws[i] = 0.0f;
  gg.sync();

  __shared__ float s_a[H_];
  __shared__ float s_b[H_];
  __shared__ float s_red[4][4];
  __shared__ float s_val[2];

  for (int t = 0; t < T_; ++t) {
    const float* We_t = We + (size_t)t * E_ * H_;
    const float* be_t = be + (size_t)t * E_;
    const float* hread  = hbuf + (t & 1) * L_ * H_;
    float*       hwrite = hbuf + ((t + 1) & 1) * L_ * H_;

    // ================= LSTM layers =================
    #pragma unroll
    for (int l = 0; l < L_; ++l) {
      const float* inv = (l == 0) ? xv : hwrite;      // layer input vector
      const float* hol = hread + l * H_;              // previous h for this layer
      *(float4*)&s_a[c0] = *(const float4*)&inv[c0];
      *(float4*)&s_b[c0] = *(const float4*)&hol[c0];
      __syncthreads();
      const float4 xi = *(const float4*)&s_a[c0];
      const float4 hi = *(const float4*)&s_b[c0];
      const float* wih = W_ih + (size_t)l * 4 * H_ * H_;
      const float* whh = W_hh + (size_t)l * 4 * H_ * H_;

      for (int j = bid; j < H_; j += nb) {
        float a[4];
        #pragma unroll
        for (int q = 0; q < 4; ++q) {
          const float4 w1 = *(const float4*)&wih[(size_t)(q * H_ + j) * H_ + c0];
          const float4 w2 = *(const float4*)&whh[(size_t)(q * H_ + j) * H_ + c0];
          a[q] = w1.x * xi.x + w1.y * xi.y + w1.z * xi.z + w1.w * xi.w
               + w2.x * hi.x + w2.y * hi.y + w2.z * hi.z + w2.w * hi.w;
        }
        #pragma unroll
        for (int off = 32; off; off >>= 1) {
          a[0] += __shfl_down(a[0], off, 64);
          a[1] += __shfl_down(a[1], off, 64);
          a[2] += __shfl_down(a[2], off, 64);
          a[3] += __shfl_down(a[3], off, 64);
        }
        if (lane == 0) {
          s_red[wv][0] = a[0]; s_red[wv][1] = a[1];
          s_red[wv][2] = a[2]; s_red[wv][3] = a[3];
        }
        __syncthreads();
        if (tid == 0) {
          float g[4];
          #pragma unroll
          for (int q = 0; q < 4; ++q)
            g[q] = s_red[0][q] + s_red[1][q] + s_red[2][q] + s_red[3][q]
                 + b_ih[(size_t)(l * 4 + q) * H_ + j] + b_hh[(size_t)(l * 4 + q) * H_ + j];
          const float ig = sigm(g[0]);
          const float fg = sigm(g[1]);
          const float gv = tanhf(g[2]);
          const float og = sigm(g[3]);
          const float cn = fg * cst[l * H_ + j] + ig * gv;
          cst[l * H_ + j] = cn;
          hwrite[l * H_ + j] = og * tanhf(cn);
        }
        __syncthreads();
      }
      gg.sync();
    }

    // ================= logits =================
    *(float4*)&s_a[c0] = *(const float4*)&hwrite[(L_ - 1) * H_ + c0];
    __syncthreads();
    const float4 h2 = *(const float4*)&s_a[c0];
    for (int j = bid; j < E_; j += nb) {
      const float4 w = *(const float4*)&We_t[(size_t)j * H_ + c0];
      float a0 = w.x * h2.x + w.y * h2.y + w.z * h2.z + w.w * h2.w;
      #pragma unroll
      for (int off = 32; off; off >>= 1) a0 += __shfl_down(a0, off, 64);
      if (lane == 0) s_red[wv][0] = a0;
      __syncthreads();
      if (tid == 0)
        logits[j] = s_red[0][0] + s_red[1][0] + s_red[2][0] + s_red[3][0] + be_t[j];
      __syncthreads();
    }
    gg.sync();

    // ======== softmax + decisions + x_next partials ========
    if (bid < PBLK) {
      const float4 lg = *(const float4*)&logits[c0];
      *(float4*)&s_a[c0] = lg;
      float m = fmaxf(fmaxf(lg.x, lg.y), fmaxf(lg.z, lg.w));
      #pragma unroll
      for (int off = 32; off; off >>= 1) m = fmaxf(m, __shfl_down(m, off, 64));
      if (lane == 0) s_red[wv][0] = m;
      __syncthreads();
      if (tid == 0)
        s_val[0] = fmaxf(fmaxf(s_red[0][0], s_red[1][0]), fmaxf(s_red[2][0], s_red[3][0]));
      __syncthreads();
      const float mx = s_val[0];
      float se = expf(lg.x - mx) + expf(lg.y - mx) + expf(lg.z - mx) + expf(lg.w - mx);
      #pragma unroll
      for (int off = 32; off; off >>= 1) se += __shfl_down(se, off, 64);
      if (lane == 0) s_red[wv][1] = se;
      __syncthreads();
      if (tid == 0)
        s_val[1] = 1.0f / (s_red[0][1] + s_red[1][1] + s_red[2][1] + s_red[3][1]);
      __syncthreads();
      const float inv_sum = s_val[1];

      float4 acc = make_float4(0.f, 0.f, 0.f, 0.f);
      const int e0 = bid * ROWS_PER_PBLK;
      #pragma unroll
      for (int r = 0; r < ROWS_PER_PBLK; ++r) {
        const int e = e0 + r;
        const float d = expf(s_a[e] - mx) * inv_sum;  // identical across all threads
        const float4 w = *(const float4*)&We_t[(size_t)e * H_ + c0];
        acc.x += d * w.x; acc.y += d * w.y; acc.z += d * w.z; acc.w += d * w.w;
      }
      *(float4*)&partial[(size_t)bid * H_ + c0] = acc;
      if (tid < ROWS_PER_PBLK) {
        const int e = e0 + tid;
        out[(size_t)t * E_ + e] = expf(s_a[e] - mx) * inv_sum;
      }
    }
    gg.sync();

    // ================= reduce partials -> x_next =================
    if (bid < 4) {
      const int col = bid * BT + tid;
      float s = 0.f;
      #pragma unroll 8
      for (int p = 0; p < PBLK; ++p) s += partial[(size_t)p * H_ + col];
      xv[col] = s;
    }
    gg.sync();
  }
}

extern "C" void kernel_launch(void* const* d_in, const int* in_sizes, int n_in,
                              void* d_out, int out_size, void* d_ws, size_t ws_size,
                              hipStream_t stream) {
  const float* W_ih = (const float*)d_in[0];
  const float* W_hh = (const float*)d_in[1];
  const float* b_ih = (const float*)d_in[2];
  const float* b_hh = (const float*)d_in[3];
  const float* We   = (const float*)d_in[4];
  const float* be   = (const float*)d_in[5];
  float* out = (float*)d_out;
  float* ws  = (float*)d_ws;

  // size the cooperative grid from real occupancy (all phases are
  // grid-stride / masked, so any grid in [PBLK, 1024] is correct)
  int grid = 1024;
  int occ = 0;
  if (hipOccupancyMaxActiveBlocksPerMultiprocessor(&occ, (const void*)ctrl_kernel, BT, 0) == hipSuccess
      && occ > 0) {
    int nCU = 256;
    hipDeviceProp_t props;
    int dev = 0;
    if (hipGetDevice(&dev) == hipSuccess &&
        hipGetDeviceProperties(&props, dev) == hipSuccess &&
        props.multiProcessorCount > 0)
      nCU = props.multiProcessorCount;
    long cap = (long)occ * (long)nCU;
    if (cap < grid) grid = (int)cap;
  }
  if (grid < PBLK) grid = PBLK;  // required by the softmax/feedback phase

  void* args[] = {(void*)&W_ih, (void*)&W_hh, (void*)&b_ih, (void*)&b_hh,
                  (void*)&We,   (void*)&be,   (void*)&out,  (void*)&ws};
  (void)hipLaunchCooperativeKernel((const void*)ctrl_kernel, dim3(grid), dim3(BT),
                                   args, 0, stream);
}

// Round 2
// 7752.137 us; speedup vs baseline: 2.4366x; 2.4366x over previous
//
#include <hip/hip_runtime.h>
#include <hip/hip_cooperative_groups.h>

namespace cg = cooperative_groups;

static constexpr int L_ = 2;      // layers
static constexpr int H_ = 1024;   // hidden
static constexpr int E_ = 1024;   // embedding
static constexpr int T_ = 64;     // steps
static constexpr int NB = 256;    // blocks (== CUs; weights partitioned exactly)
static constexpr int BT = 1024;   // threads per block (16 waves)
static constexpr int XB = 16;     // blocks active in softmax/feedback phase (64 cols each)

__device__ __forceinline__ float sigm(float v) { return 1.0f / (1.0f + expf(-v)); }

// Weight-stationary persistent controller.
// Wave w of block b permanently holds, in 64 VGPRs (float4 wr[4][4]):
//   matrix-half (l = w>>3, q = (w>>1)&3, half = w&1 : 0=W_ih/x, 1=W_hh/h)
//   rows j = 4b+u (u=0..3), columns k = m*256 + lane*4 + {0..3}.
__global__ __launch_bounds__(BT, 4) void ctrl_kernel(
    const float* __restrict__ W_ih, const float* __restrict__ W_hh,
    const float* __restrict__ b_ih, const float* __restrict__ b_hh,
    const float* __restrict__ We,   const float* __restrict__ be,
    float* __restrict__ out, float* __restrict__ ws)
{
  cg::grid_group gg = cg::this_grid();
  const int tid  = threadIdx.x;
  const int b    = blockIdx.x;
  const int lane = tid & 63;
  const int w    = tid >> 6;       // wave 0..15
  const int wl   = w >> 3;         // layer this wave serves
  const int wq   = (w >> 1) & 3;   // gate index (i,f,g,o)
  const int wh   = w & 1;          // 0: W_ih (x-half), 1: W_hh (h-half)

  // workspace (floats): xv[H] | hbuf[2][L][H] | logits[E]
  float* xv     = ws;
  float* hbuf   = ws + H_;
  float* logits = hbuf + 2 * L_ * H_;

  __shared__ float  s_x[H_];           // layer input / logits staging
  __shared__ float  s_h[H_];           // prev hidden staging
  __shared__ float  s_gd[4][2][4];     // gate dot partials [q][half][unit]
  __shared__ float  s_bias[2][4][4];   // combined biases [l][q][unit]
  __shared__ float  s_c[2][4];         // cell state [l][unit]
  __shared__ float  s_red[16];         // per-wave reduction scratch
  __shared__ float4 s_part[16][16];    // xnext col partials [wave][colgrp]

  // ---- prologue: zero global state, stage biases, load weights to VGPRs ----
  {
    const int i = b * BT + tid;
    if (i < H_ + 2 * L_ * H_) ws[i] = 0.0f;   // xv + hbuf
  }
  if (tid < 32) {
    const int l = tid >> 4, q = (tid >> 2) & 3, u = tid & 3;
    const int j = b * 4 + u;
    s_bias[l][q][u] = b_ih[(size_t)l * 4 * H_ + q * H_ + j]
                    + b_hh[(size_t)l * 4 * H_ + q * H_ + j];
  }
  if (tid < 8) s_c[tid >> 2][tid & 3] = 0.0f;

  float4 wr[4][4];
  {
    const float* Wbase = (wh == 0) ? W_ih : W_hh;
    #pragma unroll
    for (int u = 0; u < 4; ++u) {
      const size_t row = (size_t)wl * 4 * H_ * H_
                       + ((size_t)wq * H_ + (size_t)(b * 4 + u)) * (size_t)H_;
      #pragma unroll
      for (int m = 0; m < 4; ++m)
        wr[u][m] = *(const float4*)&Wbase[row + (size_t)m * 256 + lane * 4];
    }
  }
  gg.sync();

  for (int t = 0; t < T_; ++t) {
    const int cur = t & 1, nxt = cur ^ 1;
    const float* We_t = We + (size_t)t * E_ * H_;
    const float* be_t = be + (size_t)t * E_;

    // ================= LSTM layers (weights in registers) =================
    #pragma unroll
    for (int l = 0; l < L_; ++l) {
      s_x[tid] = (l == 0) ? xv[tid] : hbuf[(size_t)nxt * L_ * H_ + tid];
      s_h[tid] = hbuf[(size_t)cur * L_ * H_ + l * H_ + tid];
      __syncthreads();
      if (wl == l) {
        const float4* vin = (const float4*)((wh == 0) ? s_x : s_h);
        float a0 = 0.f, a1 = 0.f, a2 = 0.f, a3 = 0.f;
        #pragma unroll
        for (int m = 0; m < 4; ++m) {
          const float4 x4 = vin[m * 64 + lane];
          a0 += wr[0][m].x * x4.x + wr[0][m].y * x4.y + wr[0][m].z * x4.z + wr[0][m].w * x4.w;
          a1 += wr[1][m].x * x4.x + wr[1][m].y * x4.y + wr[1][m].z * x4.z + wr[1][m].w * x4.w;
          a2 += wr[2][m].x * x4.x + wr[2][m].y * x4.y + wr[2][m].z * x4.z + wr[2][m].w * x4.w;
          a3 += wr[3][m].x * x4.x + wr[3][m].y * x4.y + wr[3][m].z * x4.z + wr[3][m].w * x4.w;
        }
        #pragma unroll
        for (int off = 32; off; off >>= 1) {
          a0 += __shfl_down(a0, off, 64);
          a1 += __shfl_down(a1, off, 64);
          a2 += __shfl_down(a2, off, 64);
          a3 += __shfl_down(a3, off, 64);
        }
        if (lane == 0) {
          s_gd[wq][wh][0] = a0; s_gd[wq][wh][1] = a1;
          s_gd[wq][wh][2] = a2; s_gd[wq][wh][3] = a3;
        }
      }
      __syncthreads();
      if (tid < 4) {
        const int u = tid;
        const float g0 = s_gd[0][0][u] + s_gd[0][1][u] + s_bias[l][0][u];
        const float g1 = s_gd[1][0][u] + s_gd[1][1][u] + s_bias[l][1][u];
        const float g2 = s_gd[2][0][u] + s_gd[2][1][u] + s_bias[l][2][u];
        const float g3 = s_gd[3][0][u] + s_gd[3][1][u] + s_bias[l][3][u];
        const float cn = sigm(g1) * s_c[l][u] + sigm(g0) * tanhf(g2);
        s_c[l][u] = cn;
        hbuf[(size_t)nxt * L_ * H_ + l * H_ + b * 4 + u] = sigm(g3) * tanhf(cn);
      }
      gg.sync();
    }

    // ================= logits: block b computes rows 4b..4b+3 =================
    s_x[tid] = hbuf[(size_t)nxt * L_ * H_ + H_ + tid];   // top hidden
    __syncthreads();
    {
      const int rr = tid >> 8;          // row within block (0..3)
      const int ii = tid & 255;
      const float4 w4 = *(const float4*)&We_t[((size_t)(b * 4 + rr)) * H_ + ii * 4];
      const float4 h4 = ((const float4*)s_x)[ii];
      float a = w4.x * h4.x + w4.y * h4.y + w4.z * h4.z + w4.w * h4.w;
      #pragma unroll
      for (int off = 32; off; off >>= 1) a += __shfl_down(a, off, 64);
      if (lane == 0) s_red[w] = a;
      __syncthreads();
      if ((tid & 255) == 0) {
        const int e = b * 4 + rr;
        logits[e] = s_red[rr * 4] + s_red[rr * 4 + 1] + s_red[rr * 4 + 2]
                  + s_red[rr * 4 + 3] + be_t[e];
      }
    }
    gg.sync();

    // ======== softmax + decisions + x_next (blocks 0..XB-1, 64 cols each) ========
    if (b < XB) {
      s_x[tid] = logits[tid];
      __syncthreads();
      const float v = s_x[tid];
      float mm = v;
      #pragma unroll
      for (int off = 32; off; off >>= 1) mm = fmaxf(mm, __shfl_down(mm, off, 64));
      if (lane == 0) s_red[w] = mm;
      __syncthreads();
      mm = s_red[0];
      #pragma unroll
      for (int k = 1; k < 16; ++k) mm = fmaxf(mm, s_red[k]);
      float ev = expf(v - mm);
      __syncthreads();                   // s_red reuse
      float sv = ev;
      #pragma unroll
      for (int off = 32; off; off >>= 1) sv += __shfl_down(sv, off, 64);
      if (lane == 0) s_red[w] = sv;
      __syncthreads();
      float ssum = 0.f;
      #pragma unroll
      for (int k = 0; k < 16; ++k) ssum += s_red[k];
      const float inv = 1.0f / ssum;

      if (tid < 64)
        out[(size_t)t * E_ + b * 64 + tid] = expf(s_x[b * 64 + tid] - mm) * inv;

      // x_next[64b + c] = sum_e d(e) * We_t[e][64b + c]
      const int cl = tid & 15;   // float4 col group within the 64-col slice
      const int eo = tid >> 4;   // 0..63
      float4 acc = make_float4(0.f, 0.f, 0.f, 0.f);
      #pragma unroll
      for (int it = 0; it < 16; ++it) {
        const int e = it * 64 + eo;
        const float d = expf(s_x[e] - mm) * inv;
        const float4 w4 = *(const float4*)&We_t[(size_t)e * H_ + b * 64 + cl * 4];
        acc.x += d * w4.x; acc.y += d * w4.y; acc.z += d * w4.z; acc.w += d * w4.w;
      }
      // reduce the 4 eo-groups within each wave (lanes 0..15 keep result)
      acc.x += __shfl_down(acc.x, 32, 64); acc.y += __shfl_down(acc.y, 32, 64);
      acc.z += __shfl_down(acc.z, 32, 64); acc.w += __shfl_down(acc.w, 32, 64);
      acc.x += __shfl_down(acc.x, 16, 64); acc.y += __shfl_down(acc.y, 16, 64);
      acc.z += __shfl_down(acc.z, 16, 64); acc.w += __shfl_down(acc.w, 16, 64);
      if (lane < 16) s_part[w][lane] = acc;
      __syncthreads();
      if (tid < 64) {
        const float* sp = (const float*)s_part;
        float s = 0.f;
        #pragma unroll
        for (int k = 0; k < 16; ++k) s += sp[k * 64 + tid];
        xv[b * 64 + tid] = s;
      }
    }
    gg.sync();
  }
}

extern "C" void kernel_launch(void* const* d_in, const int* in_sizes, int n_in,
                              void* d_out, int out_size, void* d_ws, size_t ws_size,
                              hipStream_t stream) {
  const float* W_ih = (const float*)d_in[0];
  const float* W_hh = (const float*)d_in[1];
  const float* b_ih = (const float*)d_in[2];
  const float* b_hh = (const float*)d_in[3];
  const float* We   = (const float*)d_in[4];
  const float* be   = (const float*)d_in[5];
  float* out = (float*)d_out;
  float* ws  = (float*)d_ws;

  void* args[] = {(void*)&W_ih, (void*)&W_hh, (void*)&b_ih, (void*)&b_hh,
                  (void*)&We,   (void*)&be,   (void*)&out,  (void*)&ws};
  (void)hipLaunchCooperativeKernel((const void*)ctrl_kernel, dim3(NB), dim3(BT),
                                   args, 0, stream);
}

// Round 3
// 7545.006 us; speedup vs baseline: 2.5035x; 1.0275x over previous
//
#include <hip/hip_runtime.h>
#include <hip/hip_cooperative_groups.h>

namespace cg = cooperative_groups;

static constexpr int L_ = 2;      // layers
static constexpr int H_ = 1024;   // hidden
static constexpr int E_ = 1024;   // embedding
static constexpr int T_ = 64;     // steps
static constexpr int NB = 256;    // blocks (== CUs; weights partitioned exactly)
static constexpr int BT = 1024;   // threads per block (16 waves)

__device__ __forceinline__ float sigm(float v) { return 1.0f / (1.0f + expf(-v)); }

// Weight-stationary persistent controller.
// Wave w of block b permanently holds, in 64 VGPRs (float4 wr[4][4]):
//   matrix-half (l = w>>3, q = (w>>1)&3, half = w&1 : 0=W_ih/x, 1=W_hh/h)
//   rows j = 4b+u (u=0..3), columns k = m*256 + lane*4 + {0..3}.
// The asm pins below make the weight values opaque so the compiler cannot
// re-materialize them from global memory inside the t-loop (R2 failure mode).
__global__ __launch_bounds__(BT, 4) void ctrl_kernel(
    const float* __restrict__ W_ih, const float* __restrict__ W_hh,
    const float* __restrict__ b_ih, const float* __restrict__ b_hh,
    const float* __restrict__ We,   const float* __restrict__ be,
    float* __restrict__ out, float* __restrict__ ws)
{
  cg::grid_group gg = cg::this_grid();
  const int tid  = threadIdx.x;
  const int b    = blockIdx.x;
  const int lane = tid & 63;
  const int w    = tid >> 6;       // wave 0..15
  const int wl   = w >> 3;         // layer this wave serves
  const int wq   = (w >> 1) & 3;   // gate index (i,f,g,o)
  const int wh   = w & 1;          // 0: W_ih (x-half), 1: W_hh (h-half)

  // workspace (floats): xv[H] | hbuf[2][L][H] | logits[E]
  float* xv     = ws;
  float* hbuf   = ws + H_;
  float* logits = hbuf + 2 * L_ * H_;

  __shared__ float  s_x[H_];           // staging: layer input / logits
  __shared__ float  s_h[H_];           // staging: prev hidden
  __shared__ float  s_gd[4][2][4];     // gate dot partials [q][half][unit]
  __shared__ float  s_bias[2][4][4];   // combined biases [l][q][unit]
  __shared__ float  s_c[2][4];         // cell state [l][unit]
  __shared__ float  s_red[16];         // per-wave reduction scratch (logits)
  __shared__ float  s_redm[16];        // softmax max partials
  __shared__ float  s_reds[16];        // softmax sum partials
  __shared__ float4 s_part4[16];       // x_next per-wave partials (4 cols)

  // ---- prologue: zero global state, stage biases, load weights to VGPRs ----
  {
    const int i = b * BT + tid;
    if (i < H_ + 2 * L_ * H_) ws[i] = 0.0f;   // xv + hbuf
  }
  if (tid < 32) {
    const int l = tid >> 4, q = (tid >> 2) & 3, u = tid & 3;
    const int j = b * 4 + u;
    s_bias[l][q][u] = b_ih[(size_t)l * 4 * H_ + q * H_ + j]
                    + b_hh[(size_t)l * 4 * H_ + q * H_ + j];
  }
  if (tid < 8) s_c[tid >> 2][tid & 3] = 0.0f;

  float4 wr[4][4];
  {
    const float* Wbase = (wh == 0) ? W_ih : W_hh;
    #pragma unroll
    for (int u = 0; u < 4; ++u) {
      const size_t row = (size_t)wl * 4 * H_ * H_
                       + ((size_t)wq * H_ + (size_t)(b * 4 + u)) * (size_t)H_;
      #pragma unroll
      for (int m = 0; m < 4; ++m)
        wr[u][m] = *(const float4*)&Wbase[row + (size_t)m * 256 + lane * 4];
    }
  }
  // pin: values become opaque -> must stay live in VGPRs for the whole kernel
  #pragma unroll
  for (int u = 0; u < 4; ++u) {
    #pragma unroll
    for (int m = 0; m < 4; ++m)
      asm volatile("" : "+v"(wr[u][m].x), "+v"(wr[u][m].y),
                        "+v"(wr[u][m].z), "+v"(wr[u][m].w));
  }
  gg.sync();

  for (int t = 0; t < T_; ++t) {
    const int cur = t & 1, nxt = cur ^ 1;
    const float* We_t = We + (size_t)t * E_ * H_;
    const float* be_t = be + (size_t)t * E_;

    // ================= LSTM layers (weights in registers) =================
    #pragma unroll
    for (int l = 0; l < L_; ++l) {
      s_x[tid] = (l == 0) ? xv[tid] : hbuf[(size_t)nxt * L_ * H_ + tid];
      s_h[tid] = hbuf[(size_t)cur * L_ * H_ + l * H_ + tid];
      __syncthreads();
      if (wl == l) {
        const float4* vin = (const float4*)((wh == 0) ? s_x : s_h);
        float a0 = 0.f, a1 = 0.f, a2 = 0.f, a3 = 0.f;
        #pragma unroll
        for (int m = 0; m < 4; ++m) {
          const float4 x4 = vin[m * 64 + lane];
          a0 += wr[0][m].x * x4.x + wr[0][m].y * x4.y + wr[0][m].z * x4.z + wr[0][m].w * x4.w;
          a1 += wr[1][m].x * x4.x + wr[1][m].y * x4.y + wr[1][m].z * x4.z + wr[1][m].w * x4.w;
          a2 += wr[2][m].x * x4.x + wr[2][m].y * x4.y + wr[2][m].z * x4.z + wr[2][m].w * x4.w;
          a3 += wr[3][m].x * x4.x + wr[3][m].y * x4.y + wr[3][m].z * x4.z + wr[3][m].w * x4.w;
        }
        #pragma unroll
        for (int off = 32; off; off >>= 1) {
          a0 += __shfl_down(a0, off, 64);
          a1 += __shfl_down(a1, off, 64);
          a2 += __shfl_down(a2, off, 64);
          a3 += __shfl_down(a3, off, 64);
        }
        if (lane == 0) {
          s_gd[wq][wh][0] = a0; s_gd[wq][wh][1] = a1;
          s_gd[wq][wh][2] = a2; s_gd[wq][wh][3] = a3;
        }
      }
      __syncthreads();
      if (tid < 4) {
        const int u = tid;
        const float g0 = s_gd[0][0][u] + s_gd[0][1][u] + s_bias[l][0][u];
        const float g1 = s_gd[1][0][u] + s_gd[1][1][u] + s_bias[l][1][u];
        const float g2 = s_gd[2][0][u] + s_gd[2][1][u] + s_bias[l][2][u];
        const float g3 = s_gd[3][0][u] + s_gd[3][1][u] + s_bias[l][3][u];
        const float cn = sigm(g1) * s_c[l][u] + sigm(g0) * tanhf(g2);
        s_c[l][u] = cn;
        hbuf[(size_t)nxt * L_ * H_ + l * H_ + b * 4 + u] = sigm(g3) * tanhf(cn);
      }
      gg.sync();
    }

    // ================= logits: block b computes rows 4b..4b+3 =================
    s_x[tid] = hbuf[(size_t)nxt * L_ * H_ + H_ + tid];   // top hidden
    __syncthreads();
    {
      const int rr = tid >> 8;          // row within block (0..3)
      const int ii = tid & 255;
      const float4 w4 = *(const float4*)&We_t[((size_t)(b * 4 + rr)) * H_ + ii * 4];
      const float4 h4 = ((const float4*)s_x)[ii];
      float a = w4.x * h4.x + w4.y * h4.y + w4.z * h4.z + w4.w * h4.w;
      #pragma unroll
      for (int off = 32; off; off >>= 1) a += __shfl_down(a, off, 64);
      if (lane == 0) s_red[w] = a;
      __syncthreads();
      if ((tid & 255) == 0) {
        const int e = b * 4 + rr;
        logits[e] = s_red[rr * 4] + s_red[rr * 4 + 1] + s_red[rr * 4 + 2]
                  + s_red[rr * 4 + 3] + be_t[e];
      }
    }
    gg.sync();

    // ==== softmax + decisions + x_next: ALL blocks, block b owns cols 4b..4b+3 ====
    {
      s_x[tid] = logits[tid];
      __syncthreads();
      const float v = s_x[tid];
      float mm = v;
      #pragma unroll
      for (int off = 32; off; off >>= 1) mm = fmaxf(mm, __shfl_down(mm, off, 64));
      if (lane == 0) s_redm[w] = mm;
      __syncthreads();
      mm = s_redm[0];
      #pragma unroll
      for (int k = 1; k < 16; ++k) mm = fmaxf(mm, s_redm[k]);
      const float ev = expf(v - mm);        // e = tid
      float sv = ev;
      #pragma unroll
      for (int off = 32; off; off >>= 1) sv += __shfl_down(sv, off, 64);
      if (lane == 0) s_reds[w] = sv;
      __syncthreads();
      float ssum = 0.f;
      #pragma unroll
      for (int k = 0; k < 16; ++k) ssum += s_reds[k];
      const float inv = 1.0f / ssum;
      const float d = ev * inv;             // decision[e = tid], all blocks agree

      if ((tid >> 2) == b) out[(size_t)t * E_ + tid] = d;  // block b writes its 4

      // x_next[4b + k] = sum_e d(e) * We_t[e][4b + k]  (thread = one e)
      const float4 w4 = *(const float4*)&We_t[(size_t)tid * H_ + b * 4];
      float4 acc = make_float4(d * w4.x, d * w4.y, d * w4.z, d * w4.w);
      #pragma unroll
      for (int off = 32; off; off >>= 1) {
        acc.x += __shfl_down(acc.x, off, 64);
        acc.y += __shfl_down(acc.y, off, 64);
        acc.z += __shfl_down(acc.z, off, 64);
        acc.w += __shfl_down(acc.w, off, 64);
      }
      if (lane == 0) s_part4[w] = acc;
      __syncthreads();
      if (tid < 4) {
        float s = 0.f;
        #pragma unroll
        for (int k = 0; k < 16; ++k)
          s += ((const float*)&s_part4[k])[tid];
        xv[b * 4 + tid] = s;
      }
    }
    gg.sync();
  }
}

extern "C" void kernel_launch(void* const* d_in, const int* in_sizes, int n_in,
                              void* d_out, int out_size, void* d_ws, size_t ws_size,
                              hipStream_t stream) {
  const float* W_ih = (const float*)d_in[0];
  const float* W_hh = (const float*)d_in[1];
  const float* b_ih = (const float*)d_in[2];
  const float* b_hh = (const float*)d_in[3];
  const float* We   = (const float*)d_in[4];
  const float* be   = (const float*)d_in[5];
  float* out = (float*)d_out;
  float* ws  = (float*)d_ws;

  void* args[] = {(void*)&W_ih, (void*)&W_hh, (void*)&b_ih, (void*)&b_hh,
                  (void*)&We,   (void*)&be,   (void*)&out,  (void*)&ws};
  (void)hipLaunchCooperativeKernel((const void*)ctrl_kernel, dim3(NB), dim3(BT),
                                   args, 0, stream);
}

// Round 4
// 4789.421 us; speedup vs baseline: 3.9438x; 1.5753x over previous
//
#include <hip/hip_runtime.h>

static constexpr int L_ = 2;      // layers
static constexpr int H_ = 1024;   // hidden
static constexpr int E_ = 1024;   // embedding
static constexpr int T_ = 64;     // steps
static constexpr int NB = 256;    // blocks (== CUs; weights partitioned exactly)
static constexpr int BT = 1024;   // threads per block (16 waves)

// ws layout (floats): xv[H] | hbuf[2][L][H] | logits[E] | counters[T*4]
static constexpr int WS_XV  = 0;
static constexpr int WS_HB  = H_;
static constexpr int WS_LG  = H_ + 2 * L_ * H_;
static constexpr int WS_CNT = WS_LG + E_;            // unsigned counters
static constexpr int NSYNC  = T_ * 4;
static constexpr size_t WS_ZERO_BYTES = (size_t)(WS_CNT + NSYNC) * 4;

__device__ __forceinline__ float sigm(float v) { return 1.0f / (1.0f + expf(-v)); }

// Lean grid barrier: one counter per sync point (zeroed by hipMemsetAsync
// before launch). No ockl call, no s_sleep(127) backoff: ~2-3 us instead
// of the measured 29 us of cg::grid_group::sync().
__device__ __forceinline__ void gsync(unsigned* cnt) {
  __syncthreads();
  if (threadIdx.x == 0) {
    __threadfence();  // agent-scope release: publish this block's writes
    __hip_atomic_fetch_add(cnt, 1u, __ATOMIC_RELAXED, __HIP_MEMORY_SCOPE_AGENT);
    while (__hip_atomic_load(cnt, __ATOMIC_RELAXED, __HIP_MEMORY_SCOPE_AGENT) < (unsigned)NB)
      __builtin_amdgcn_s_sleep(1);
    __threadfence();  // agent-scope acquire: see all other blocks' writes
  }
  __syncthreads();
}

// Weight-stationary persistent controller.
// Wave w of block b permanently holds, in 64 registers (float4 wr[4][4]):
//   matrix-half (l = w>>3, q = (w>>1)&3, half = w&1 : 0=W_ih/x, 1=W_hh/h)
//   rows j = 4b+u (u=0..3), columns k = m*256 + lane*4 + {0..3}.
__global__ __launch_bounds__(BT, 4) void ctrl_kernel(
    const float* __restrict__ W_ih, const float* __restrict__ W_hh,
    const float* __restrict__ b_ih, const float* __restrict__ b_hh,
    const float* __restrict__ We,   const float* __restrict__ be,
    float* __restrict__ out, float* __restrict__ ws)
{
  const int tid  = threadIdx.x;
  const int b    = blockIdx.x;
  const int lane = tid & 63;
  const int w    = tid >> 6;       // wave 0..15
  const int wl   = w >> 3;         // layer this wave serves
  const int wq   = (w >> 1) & 3;   // gate index (i,f,g,o)
  const int wh   = w & 1;          // 0: W_ih (x-half), 1: W_hh (h-half)

  float*    xv     = ws + WS_XV;
  float*    hbuf   = ws + WS_HB;
  float*    logits = ws + WS_LG;
  unsigned* cnt    = (unsigned*)(ws + WS_CNT);

  // feedback column ownership, XCD-swizzled: the 4 blocks sharing one 64B
  // We line ((b&7) equal) land on the same XCD under round-robin dispatch.
  const int cswz = ((b & 7) * 32 + (b >> 3)) * 4;

  __shared__ float  s_x[H_];           // staging: layer input / logits
  __shared__ float  s_h[H_];           // staging: prev hidden
  __shared__ float  s_gd[4][2][4];     // gate dot partials [q][half][unit]
  __shared__ float  s_bias[2][4][4];   // combined biases [l][q][unit]
  __shared__ float  s_c[2][4];         // cell state [l][unit]
  __shared__ float  s_red[16];         // per-wave reduction scratch
  __shared__ float  s_redm[16];        // softmax max partials
  __shared__ float  s_reds[16];        // softmax sum partials
  __shared__ float4 s_part4[16];       // x_next per-wave partials (4 cols)

  // ---- prologue: stage biases, load weights into registers ----
  if (tid < 32) {
    const int l = tid >> 4, q = (tid >> 2) & 3, u = tid & 3;
    const int j = b * 4 + u;
    s_bias[l][q][u] = b_ih[(size_t)l * 4 * H_ + q * H_ + j]
                    + b_hh[(size_t)l * 4 * H_ + q * H_ + j];
  }
  if (tid < 8) s_c[tid >> 2][tid & 3] = 0.0f;

  float4 wr[4][4];
  {
    const float* Wbase = (wh == 0) ? W_ih : W_hh;
    #pragma unroll
    for (int u = 0; u < 4; ++u) {
      const size_t row = (size_t)wl * 4 * H_ * H_
                       + ((size_t)wq * H_ + (size_t)(b * 4 + u)) * (size_t)H_;
      #pragma unroll
      for (int m = 0; m < 4; ++m)
        wr[u][m] = *(const float4*)&Wbase[row + (size_t)m * 256 + lane * 4];
    }
  }
  // pin: values opaque -> cannot be re-materialized from memory in the loop
  #pragma unroll
  for (int u = 0; u < 4; ++u) {
    #pragma unroll
    for (int m = 0; m < 4; ++m)
      asm volatile("" : "+v"(wr[u][m].x), "+v"(wr[u][m].y),
                        "+v"(wr[u][m].z), "+v"(wr[u][m].w));
  }
  // xv/hbuf/counters are zeroed by the hipMemsetAsync issued before launch;
  // no cross-block dependency before the first in-loop sync.

  for (int t = 0; t < T_; ++t) {
    const int cur = t & 1, nxt = cur ^ 1;
    const float* We_t = We + (size_t)t * E_ * H_;
    const float* be_t = be + (size_t)t * E_;
    unsigned* c4 = cnt + t * 4;

    // prefetch this step's We operands; loads overlap the LSTM phases
    const float4 wlog = *(const float4*)&We_t[((size_t)(b * 4 + (tid >> 8))) * H_ + (tid & 255) * 4];
    const float4 wfb  = *(const float4*)&We_t[(size_t)tid * H_ + cswz];

    // ================= LSTM layers (weights in registers) =================
    #pragma unroll
    for (int l = 0; l < L_; ++l) {
      s_x[tid] = (l == 0) ? xv[tid] : hbuf[(size_t)nxt * L_ * H_ + tid];
      s_h[tid] = hbuf[(size_t)cur * L_ * H_ + l * H_ + tid];
      __syncthreads();
      if (wl == l) {
        const float4* vin = (const float4*)((wh == 0) ? s_x : s_h);
        float a0 = 0.f, a1 = 0.f, a2 = 0.f, a3 = 0.f;
        #pragma unroll
        for (int m = 0; m < 4; ++m) {
          const float4 x4 = vin[m * 64 + lane];
          a0 += wr[0][m].x * x4.x + wr[0][m].y * x4.y + wr[0][m].z * x4.z + wr[0][m].w * x4.w;
          a1 += wr[1][m].x * x4.x + wr[1][m].y * x4.y + wr[1][m].z * x4.z + wr[1][m].w * x4.w;
          a2 += wr[2][m].x * x4.x + wr[2][m].y * x4.y + wr[2][m].z * x4.z + wr[2][m].w * x4.w;
          a3 += wr[3][m].x * x4.x + wr[3][m].y * x4.y + wr[3][m].z * x4.z + wr[3][m].w * x4.w;
        }
        #pragma unroll
        for (int off = 32; off; off >>= 1) {
          a0 += __shfl_down(a0, off, 64);
          a1 += __shfl_down(a1, off, 64);
          a2 += __shfl_down(a2, off, 64);
          a3 += __shfl_down(a3, off, 64);
        }
        if (lane == 0) {
          s_gd[wq][wh][0] = a0; s_gd[wq][wh][1] = a1;
          s_gd[wq][wh][2] = a2; s_gd[wq][wh][3] = a3;
        }
      }
      __syncthreads();
      if (tid < 4) {
        const int u = tid;
        const float g0 = s_gd[0][0][u] + s_gd[0][1][u] + s_bias[l][0][u];
        const float g1 = s_gd[1][0][u] + s_gd[1][1][u] + s_bias[l][1][u];
        const float g2 = s_gd[2][0][u] + s_gd[2][1][u] + s_bias[l][2][u];
        const float g3 = s_gd[3][0][u] + s_gd[3][1][u] + s_bias[l][3][u];
        const float cn = sigm(g1) * s_c[l][u] + sigm(g0) * tanhf(g2);
        s_c[l][u] = cn;
        hbuf[(size_t)nxt * L_ * H_ + l * H_ + b * 4 + u] = sigm(g3) * tanhf(cn);
      }
      gsync(c4 + l);
    }

    // ================= logits: block b computes rows 4b..4b+3 =================
    s_x[tid] = hbuf[(size_t)nxt * L_ * H_ + H_ + tid];   // top hidden
    __syncthreads();
    {
      const int rr = tid >> 8;          // row within block (0..3)
      const float4 h4 = ((const float4*)s_x)[tid & 255];
      float a = wlog.x * h4.x + wlog.y * h4.y + wlog.z * h4.z + wlog.w * h4.w;
      #pragma unroll
      for (int off = 32; off; off >>= 1) a += __shfl_down(a, off, 64);
      if (lane == 0) s_red[w] = a;
      __syncthreads();
      if ((tid & 255) == 0) {
        const int e = b * 4 + rr;
        logits[e] = s_red[rr * 4] + s_red[rr * 4 + 1] + s_red[rr * 4 + 2]
                  + s_red[rr * 4 + 3] + be_t[e];
      }
    }
    gsync(c4 + 2);

    // ==== softmax + decisions + x_next: all blocks; block b owns cols cswz..+3 ====
    {
      s_x[tid] = logits[tid];
      __syncthreads();
      const float v = s_x[tid];
      float mm = v;
      #pragma unroll
      for (int off = 32; off; off >>= 1) mm = fmaxf(mm, __shfl_down(mm, off, 64));
      if (lane == 0) s_redm[w] = mm;
      __syncthreads();
      mm = s_redm[0];
      #pragma unroll
      for (int k = 1; k < 16; ++k) mm = fmaxf(mm, s_redm[k]);
      const float ev = expf(v - mm);        // e = tid
      float sv = ev;
      #pragma unroll
      for (int off = 32; off; off >>= 1) sv += __shfl_down(sv, off, 64);
      if (lane == 0) s_reds[w] = sv;
      __syncthreads();
      float ssum = 0.f;
      #pragma unroll
      for (int k = 0; k < 16; ++k) ssum += s_reds[k];
      const float inv = 1.0f / ssum;
      const float d = ev * inv;             // decision[e = tid], all blocks agree

      if ((tid >> 2) == b) out[(size_t)t * E_ + tid] = d;  // block b writes its 4

      // x_next[cswz + k] = sum_e d(e) * We_t[e][cswz + k]  (thread = one e)
      float4 acc = make_float4(d * wfb.x, d * wfb.y, d * wfb.z, d * wfb.w);
      #pragma unroll
      for (int off = 32; off; off >>= 1) {
        acc.x += __shfl_down(acc.x, off, 64);
        acc.y += __shfl_down(acc.y, off, 64);
        acc.z += __shfl_down(acc.z, off, 64);
        acc.w += __shfl_down(acc.w, off, 64);
      }
      if (lane == 0) s_part4[w] = acc;
      __syncthreads();
      if (tid < 4) {
        float s = 0.f;
        #pragma unroll
        for (int k = 0; k < 16; ++k)
          s += ((const float*)&s_part4[k])[tid];
        xv[cswz + tid] = s;
      }
    }
    gsync(c4 + 3);
  }
}

extern "C" void kernel_launch(void* const* d_in, const int* in_sizes, int n_in,
                              void* d_out, int out_size, void* d_ws, size_t ws_size,
                              hipStream_t stream) {
  const float* W_ih = (const float*)d_in[0];
  const float* W_hh = (const float*)d_in[1];
  const float* b_ih = (const float*)d_in[2];
  const float* b_hh = (const float*)d_in[3];
  const float* We   = (const float*)d_in[4];
  const float* be   = (const float*)d_in[5];
  float* out = (float*)d_out;
  float* ws  = (float*)d_ws;

  // zero state + barrier counters (graph-capturable, replayed before each call)
  (void)hipMemsetAsync(ws, 0, WS_ZERO_BYTES, stream);

  void* args[] = {(void*)&W_ih, (void*)&W_hh, (void*)&b_ih, (void*)&b_hh,
                  (void*)&We,   (void*)&be,   (void*)&out,  (void*)&ws};
  (void)hipLaunchCooperativeKernel((const void*)ctrl_kernel, dim3(NB), dim3(BT),
                                   args, 0, stream);
}

// Round 5
// 1135.214 us; speedup vs baseline: 16.6388x; 4.2190x over previous
//
#include <hip/hip_runtime.h>

static constexpr int L_ = 2;      // layers
static constexpr int H_ = 1024;   // hidden
static constexpr int E_ = 1024;   // embedding
static constexpr int T_ = 64;     // steps
static constexpr int NB = 256;    // blocks (== CUs; weights partitioned exactly)
static constexpr int BT = 1024;   // threads per block (16 waves)
static constexpr int NSYNC = T_ * 4;
static constexpr int NGRP  = 16;  // barrier tree: 16 groups x 16 blocks

// ws layout (4-byte units):
//   xv[H] | hbuf[2][L][H] | logits[E] |
//   grp[NSYNC][16][16]  (one 64B line per group counter) |
//   root[NSYNC][16]     (one line per sync point) |
//   bc[NSYNC][16]       (one line per sync point)
static constexpr int WS_XV   = 0;
static constexpr int WS_HB   = H_;
static constexpr int WS_LG   = H_ + 2 * L_ * H_;
static constexpr int WS_GRP  = WS_LG + E_;
static constexpr int WS_ROOT = WS_GRP + NSYNC * NGRP * 16;
static constexpr int WS_BC   = WS_ROOT + NSYNC * 16;
static constexpr size_t WS_ZERO_BYTES = (size_t)(WS_BC + NSYNC * 16) * 4;

__device__ __forceinline__ float sigm(float v) { return 1.0f / (1.0f + expf(-v)); }

// agent-scope coherent payload transport (bypasses the non-coherent per-XCD
// L2 path; removes the need for buffer_wbl2/buffer_inv fences in the barrier)
__device__ __forceinline__ float cload(const float* p) {
  return __hip_atomic_load(p, __ATOMIC_RELAXED, __HIP_MEMORY_SCOPE_AGENT);
}
__device__ __forceinline__ void cstore(float* p, float v) {
  __hip_atomic_store(p, v, __ATOMIC_RELAXED, __HIP_MEMORY_SCOPE_AGENT);
}

// Fence-free two-level grid barrier. Correctness argument:
//  - every cross-block datum is written with cstore (write-through to the
//    coherence point) and read with cload (bypasses stale caches);
//  - the __syncthreads() below compiles to s_waitcnt vmcnt(0) + s_barrier,
//    so all of this block's coherent stores are globally visible before
//    thread 0 signals arrival;
//  - arrival: relaxed fetch_add on this group's private line (<=16-way
//    contention), last group-leader adds to root, last root arrival sets
//    the broadcast flag; everyone spins on the read-shared flag line.
__device__ __forceinline__ void gsync(unsigned* wsu, int idx, int b) {
  __syncthreads();
  if (threadIdx.x == 0) {
    unsigned* grp  = wsu + WS_GRP  + (idx * NGRP + (b >> 4)) * 16;
    unsigned* root = wsu + WS_ROOT + idx * 16;
    unsigned* bc   = wsu + WS_BC   + idx * 16;
    if (__hip_atomic_fetch_add(grp, 1u, __ATOMIC_RELAXED, __HIP_MEMORY_SCOPE_AGENT) == 15u) {
      if (__hip_atomic_fetch_add(root, 1u, __ATOMIC_RELAXED, __HIP_MEMORY_SCOPE_AGENT) == 15u)
        __hip_atomic_store(bc, 1u, __ATOMIC_RELAXED, __HIP_MEMORY_SCOPE_AGENT);
    }
    while (__hip_atomic_load(bc, __ATOMIC_RELAXED, __HIP_MEMORY_SCOPE_AGENT) == 0u)
      __builtin_amdgcn_s_sleep(1);
  }
  __syncthreads();
}

// Weight-stationary persistent controller.
// Wave w of block b permanently holds, in 64 registers (float4 wr[4][4]):
//   matrix-half (l = w>>3, q = (w>>1)&3, half = w&1 : 0=W_ih/x, 1=W_hh/h)
//   rows j = 4b+u (u=0..3), columns k = m*256 + lane*4 + {0..3}.
__global__ __launch_bounds__(BT, 4) void ctrl_kernel(
    const float* __restrict__ W_ih, const float* __restrict__ W_hh,
    const float* __restrict__ b_ih, const float* __restrict__ b_hh,
    const float* __restrict__ We,   const float* __restrict__ be,
    float* __restrict__ out, float* __restrict__ ws)
{
  const int tid  = threadIdx.x;
  const int b    = blockIdx.x;
  const int lane = tid & 63;
  const int w    = tid >> 6;       // wave 0..15
  const int wl   = w >> 3;         // layer this wave serves
  const int wq   = (w >> 1) & 3;   // gate index (i,f,g,o)
  const int wh   = w & 1;          // 0: W_ih (x-half), 1: W_hh (h-half)

  float*    xv     = ws + WS_XV;
  float*    hbuf   = ws + WS_HB;
  float*    logits = ws + WS_LG;
  unsigned* wsu    = (unsigned*)ws;

  // feedback column ownership, XCD-swizzled: the 4 blocks sharing one 64B
  // We line ((b&7) equal) land on the same XCD under round-robin dispatch.
  const int cswz = ((b & 7) * 32 + (b >> 3)) * 4;

  __shared__ float  s_x[H_];           // staging: layer input / logits
  __shared__ float  s_h[H_];           // staging: prev hidden
  __shared__ float  s_gd[4][2][4];     // gate dot partials [q][half][unit]
  __shared__ float  s_bias[2][4][4];   // combined biases [l][q][unit]
  __shared__ float  s_c[2][4];         // cell state [l][unit]
  __shared__ float  s_red[16];         // per-wave reduction scratch
  __shared__ float  s_redm[16];        // softmax max partials
  __shared__ float  s_reds[16];        // softmax sum partials
  __shared__ float4 s_part4[16];       // x_next per-wave partials (4 cols)

  // ---- prologue: stage biases, load weights into registers ----
  if (tid < 32) {
    const int l = tid >> 4, q = (tid >> 2) & 3, u = tid & 3;
    const int j = b * 4 + u;
    s_bias[l][q][u] = b_ih[(size_t)l * 4 * H_ + q * H_ + j]
                    + b_hh[(size_t)l * 4 * H_ + q * H_ + j];
  }
  if (tid < 8) s_c[tid >> 2][tid & 3] = 0.0f;

  float4 wr[4][4];
  {
    const float* Wbase = (wh == 0) ? W_ih : W_hh;
    #pragma unroll
    for (int u = 0; u < 4; ++u) {
      const size_t row = (size_t)wl * 4 * H_ * H_
                       + ((size_t)wq * H_ + (size_t)(b * 4 + u)) * (size_t)H_;
      #pragma unroll
      for (int m = 0; m < 4; ++m)
        wr[u][m] = *(const float4*)&Wbase[row + (size_t)m * 256 + lane * 4];
    }
  }
  // pin: values opaque -> cannot be re-materialized from memory in the loop
  #pragma unroll
  for (int u = 0; u < 4; ++u) {
    #pragma unroll
    for (int m = 0; m < 4; ++m)
      asm volatile("" : "+v"(wr[u][m].x), "+v"(wr[u][m].y),
                        "+v"(wr[u][m].z), "+v"(wr[u][m].w));
  }
  // xv/hbuf/counters zeroed by the pre-launch hipMemsetAsync.

  for (int t = 0; t < T_; ++t) {
    const int cur = t & 1, nxt = cur ^ 1;
    const float* We_t = We + (size_t)t * E_ * H_;
    const float* be_t = be + (size_t)t * E_;

    // prefetch this step's We operands; loads overlap the LSTM phases
    const float4 wlog = *(const float4*)&We_t[((size_t)(b * 4 + (tid >> 8))) * H_ + (tid & 255) * 4];
    const float4 wfb  = *(const float4*)&We_t[(size_t)tid * H_ + cswz];

    // ================= LSTM layers (weights in registers) =================
    #pragma unroll
    for (int l = 0; l < L_; ++l) {
      s_x[tid] = (l == 0) ? cload(&xv[tid]) : cload(&hbuf[(size_t)nxt * L_ * H_ + tid]);
      s_h[tid] = cload(&hbuf[(size_t)cur * L_ * H_ + l * H_ + tid]);
      __syncthreads();
      if (wl == l) {
        const float4* vin = (const float4*)((wh == 0) ? s_x : s_h);
        float a0 = 0.f, a1 = 0.f, a2 = 0.f, a3 = 0.f;
        #pragma unroll
        for (int m = 0; m < 4; ++m) {
          const float4 x4 = vin[m * 64 + lane];
          a0 += wr[0][m].x * x4.x + wr[0][m].y * x4.y + wr[0][m].z * x4.z + wr[0][m].w * x4.w;
          a1 += wr[1][m].x * x4.x + wr[1][m].y * x4.y + wr[1][m].z * x4.z + wr[1][m].w * x4.w;
          a2 += wr[2][m].x * x4.x + wr[2][m].y * x4.y + wr[2][m].z * x4.z + wr[2][m].w * x4.w;
          a3 += wr[3][m].x * x4.x + wr[3][m].y * x4.y + wr[3][m].z * x4.z + wr[3][m].w * x4.w;
        }
        #pragma unroll
        for (int off = 32; off; off >>= 1) {
          a0 += __shfl_down(a0, off, 64);
          a1 += __shfl_down(a1, off, 64);
          a2 += __shfl_down(a2, off, 64);
          a3 += __shfl_down(a3, off, 64);
        }
        if (lane == 0) {
          s_gd[wq][wh][0] = a0; s_gd[wq][wh][1] = a1;
          s_gd[wq][wh][2] = a2; s_gd[wq][wh][3] = a3;
        }
      }
      __syncthreads();
      if (tid < 4) {
        const int u = tid;
        const float g0 = s_gd[0][0][u] + s_gd[0][1][u] + s_bias[l][0][u];
        const float g1 = s_gd[1][0][u] + s_gd[1][1][u] + s_bias[l][1][u];
        const float g2 = s_gd[2][0][u] + s_gd[2][1][u] + s_bias[l][2][u];
        const float g3 = s_gd[3][0][u] + s_gd[3][1][u] + s_bias[l][3][u];
        const float cn = sigm(g1) * s_c[l][u] + sigm(g0) * tanhf(g2);
        s_c[l][u] = cn;
        cstore(&hbuf[(size_t)nxt * L_ * H_ + l * H_ + b * 4 + u], sigm(g3) * tanhf(cn));
      }
      gsync(wsu, t * 4 + l, b);
    }

    // ================= logits: block b computes rows 4b..4b+3 =================
    s_x[tid] = cload(&hbuf[(size_t)nxt * L_ * H_ + H_ + tid]);   // top hidden
    __syncthreads();
    {
      const int rr = tid >> 8;          // row within block (0..3)
      const float4 h4 = ((const float4*)s_x)[tid & 255];
      float a = wlog.x * h4.x + wlog.y * h4.y + wlog.z * h4.z + wlog.w * h4.w;
      #pragma unroll
      for (int off = 32; off; off >>= 1) a += __shfl_down(a, off, 64);
      if (lane == 0) s_red[w] = a;
      __syncthreads();
      if ((tid & 255) == 0) {
        const int e = b * 4 + rr;
        cstore(&logits[e], s_red[rr * 4] + s_red[rr * 4 + 1] + s_red[rr * 4 + 2]
                         + s_red[rr * 4 + 3] + be_t[e]);
      }
    }
    gsync(wsu, t * 4 + 2, b);

    // ==== softmax + decisions + x_next: all blocks; block b owns cols cswz..+3 ====
    {
      s_x[tid] = cload(&logits[tid]);
      __syncthreads();
      const float v = s_x[tid];
      float mm = v;
      #pragma unroll
      for (int off = 32; off; off >>= 1) mm = fmaxf(mm, __shfl_down(mm, off, 64));
      if (lane == 0) s_redm[w] = mm;
      __syncthreads();
      mm = s_redm[0];
      #pragma unroll
      for (int k = 1; k < 16; ++k) mm = fmaxf(mm, s_redm[k]);
      const float ev = expf(v - mm);        // e = tid
      float sv = ev;
      #pragma unroll
      for (int off = 32; off; off >>= 1) sv += __shfl_down(sv, off, 64);
      if (lane == 0) s_reds[w] = sv;
      __syncthreads();
      float ssum = 0.f;
      #pragma unroll
      for (int k = 0; k < 16; ++k) ssum += s_reds[k];
      const float inv = 1.0f / ssum;
      const float d = ev * inv;             // decision[e = tid], all blocks agree

      if ((tid >> 2) == b) out[(size_t)t * E_ + tid] = d;  // block b writes its 4

      // x_next[cswz + k] = sum_e d(e) * We_t[e][cswz + k]  (thread = one e)
      float4 acc = make_float4(d * wfb.x, d * wfb.y, d * wfb.z, d * wfb.w);
      #pragma unroll
      for (int off = 32; off; off >>= 1) {
        acc.x += __shfl_down(acc.x, off, 64);
        acc.y += __shfl_down(acc.y, off, 64);
        acc.z += __shfl_down(acc.z, off, 64);
        acc.w += __shfl_down(acc.w, off, 64);
      }
      if (lane == 0) s_part4[w] = acc;
      __syncthreads();
      if (tid < 4) {
        float s = 0.f;
        #pragma unroll
        for (int k = 0; k < 16; ++k)
          s += ((const float*)&s_part4[k])[tid];
        cstore(&xv[cswz + tid], s);
      }
    }
    gsync(wsu, t * 4 + 3, b);
  }
}

extern "C" void kernel_launch(void* const* d_in, const int* in_sizes, int n_in,
                              void* d_out, int out_size, void* d_ws, size_t ws_size,
                              hipStream_t stream) {
  const float* W_ih = (const float*)d_in[0];
  const float* W_hh = (const float*)d_in[1];
  const float* b_ih = (const float*)d_in[2];
  const float* b_hh = (const float*)d_in[3];
  const float* We   = (const float*)d_in[4];
  const float* be   = (const float*)d_in[5];
  float* out = (float*)d_out;
  float* ws  = (float*)d_ws;

  // zero state + all barrier slots (graph-capturable, replayed every call)
  (void)hipMemsetAsync(ws, 0, WS_ZERO_BYTES, stream);

  void* args[] = {(void*)&W_ih, (void*)&W_hh, (void*)&b_ih, (void*)&b_hh,
                  (void*)&We,   (void*)&be,   (void*)&out,  (void*)&ws};
  (void)hipLaunchCooperativeKernel((const void*)ctrl_kernel, dim3(NB), dim3(BT),
                                   args, 0, stream);
}